// Round 4
// baseline (313.293 us; speedup 1.0000x reference)
//
#include <hip/hip_runtime.h>
#include <hip/hip_bf16.h>
#include <math.h>

// ---------------------------------------------------------------------------
// 3-layer GAT (PyG GATConv semantics, self-loops, eval mode).
// Round-4 structure: layers 1-2 use the LINEARITY of GATConv aggregation:
//   out[d, h-block] = (sum_e alpha[e,h] * x[src_e]) @ W_h
// so we aggregate the SMALL input features (x: 128B/256B rows, L2-resident)
// instead of the projected features (h2: 2KB rows, L2-thrashing), and apply
// the per-head projection AFTER aggregation with node-blocked W reuse.
// Attention logits come from pre-projected vectors av = W_h @ a_h, so h1/h2
// are never materialized. Layer 3 (512->6) keeps project-first (rows shrink).
// alpha normalization is fused into the per-(node,head) softmax-stats kernel.
// ---------------------------------------------------------------------------

#define NEG_SLOPE 0.2f

// ---------------- CSR build ----------------

__global__ __launch_bounds__(256) void count_deg(const int* __restrict__ ei,
                                                 int* __restrict__ deg, int E) {
  int e = blockIdx.x * blockDim.x + threadIdx.x;
  if (e < E) atomicAdd(&deg[ei[E + e]], 1);  // ei[E+e] = dst
}

__global__ __launch_bounds__(1024) void scan_k(const int* __restrict__ deg,
                                               int* __restrict__ rowptr,
                                               int* __restrict__ cursor, int n) {
  __shared__ int part[1024];
  int t = threadIdx.x;
  int chunk = (n + 1023) >> 10;
  int lo = t * chunk;
  int hi = min(lo + chunk, n);
  int s = 0;
  for (int i = lo; i < hi; ++i) s += deg[i];
  part[t] = s;
  __syncthreads();
  for (int off = 1; off < 1024; off <<= 1) {
    int v = (t >= off) ? part[t - off] : 0;
    __syncthreads();
    part[t] += v;
    __syncthreads();
  }
  int run = (t == 0) ? 0 : part[t - 1];
  for (int i = lo; i < hi; ++i) {
    rowptr[i] = run;
    cursor[i] = run;
    run += deg[i];
  }
  if (t == 1023) rowptr[n] = part[1023];
}

__global__ __launch_bounds__(256) void fill_edges(const int* __restrict__ ei,
                                                  int* __restrict__ cursor,
                                                  int* __restrict__ esrc,
                                                  int* __restrict__ edst, int E) {
  int e = blockIdx.x * blockDim.x + threadIdx.x;
  if (e < E) {
    int d = ei[E + e];
    int pos = atomicAdd(&cursor[d], 1);
    esrc[pos] = ei[e];  // src
    edst[pos] = d;
  }
}

// ---------------- pre-projected attention vectors --------------------------
// avs1[h][k]=sum_c W1[k,h*8+c]*asrc1[h,c]   (k<32)   -> av[0..256)
// avd1 -> av[256..512); avs2[h][k] (k<64) -> av[512..1024); avd2 -> av[1024..1536)

__global__ __launch_bounds__(512) void prep_av(const float* __restrict__ W1,
                                               const float* __restrict__ as1,
                                               const float* __restrict__ ad1,
                                               const float* __restrict__ W2,
                                               const float* __restrict__ as2,
                                               const float* __restrict__ ad2,
                                               float* __restrict__ av) {
  int t = threadIdx.x;
  if (blockIdx.x == 0) {
    if (t < 256) {
      int h = t >> 5, k = t & 31;
      float s = 0.f, d = 0.f;
#pragma unroll
      for (int c = 0; c < 8; ++c) {
        float w = W1[k * 64 + h * 8 + c];
        s += w * as1[h * 8 + c];
        d += w * ad1[h * 8 + c];
      }
      av[t] = s;
      av[256 + t] = d;
    }
  } else {
    int h = t >> 6, k = t & 63;
    float s = 0.f, d = 0.f;
#pragma unroll
    for (int c = 0; c < 64; ++c) {
      float w = W2[k * 512 + h * 64 + c];
      s += w * as2[h * 64 + c];
      d += w * ad2[h * 64 + c];
    }
    av[512 + t] = s;
    av[1024 + t] = d;
  }
}

// ---------------- logits from input features x ------------------------------

template <int HH, int K>
__global__ __launch_bounds__(256) void logits_x(const float* __restrict__ X,
                                                const float* __restrict__ avs,
                                                const float* __restrict__ avd,
                                                float* __restrict__ als,
                                                float* __restrict__ ald,
                                                float* __restrict__ selfe, int n) {
  int idx = blockIdx.x * blockDim.x + threadIdx.x;
  if (idx >= n * HH) return;
  int node = idx / HH;
  int h = idx - node * HH;
  const float* xr = X + (size_t)node * K;
  const float* vs = avs + h * K;
  const float* vd = avd + h * K;
  float s0 = 0.f, s1 = 0.f;
#pragma unroll
  for (int k4 = 0; k4 < K / 4; ++k4) {
    float4 xv = *reinterpret_cast<const float4*>(&xr[k4 * 4]);
    float4 a = *reinterpret_cast<const float4*>(&vs[k4 * 4]);
    float4 b = *reinterpret_cast<const float4*>(&vd[k4 * 4]);
    s0 += xv.x * a.x + xv.y * a.y + xv.z * a.z + xv.w * a.w;
    s1 += xv.x * b.x + xv.y * b.y + xv.z * b.z + xv.w * b.w;
  }
  als[idx] = s0;
  ald[idx] = s1;
  float e = s0 + s1;
  selfe[idx] = e > 0.f ? e : NEG_SLOPE * e;
}

// ---------------- layer-3 logits from h3 (C=6) ------------------------------

__global__ __launch_bounds__(256) void logits_h3(const float* __restrict__ HF,
                                                 const float* __restrict__ Asrc,
                                                 const float* __restrict__ Adst,
                                                 float* __restrict__ als,
                                                 float* __restrict__ ald,
                                                 float* __restrict__ selfe, int n) {
  int node = blockIdx.x * blockDim.x + threadIdx.x;
  if (node >= n) return;
  const float* f = HF + (size_t)node * 6;
  float s0 = 0.f, s1 = 0.f;
#pragma unroll
  for (int c = 0; c < 6; ++c) {
    float v = f[c];
    s0 += v * Asrc[c];
    s1 += v * Adst[c];
  }
  als[node] = s0;
  ald[node] = s1;
  float e = s0 + s1;
  selfe[node] = e > 0.f ? e : NEG_SLOPE * e;
}

// ---------------- per-edge raw logits, layout evt[e][HH] --------------------

template <int HH>
__global__ __launch_bounds__(256) void edge_e(const int* __restrict__ esrc,
                                              const int* __restrict__ edst,
                                              const float* __restrict__ als,
                                              const float* __restrict__ ald,
                                              float* __restrict__ evt, int E) {
  int e = blockIdx.x * blockDim.x + threadIdx.x;
  if (e >= E) return;
  int s = esrc[e], d = edst[e];
  if constexpr (HH == 8) {
    float4 s0 = *reinterpret_cast<const float4*>(&als[(size_t)s * 8]);
    float4 s1 = *reinterpret_cast<const float4*>(&als[(size_t)s * 8 + 4]);
    float4 d0 = *reinterpret_cast<const float4*>(&ald[(size_t)d * 8]);
    float4 d1 = *reinterpret_cast<const float4*>(&ald[(size_t)d * 8 + 4]);
    float v[8] = {s0.x + d0.x, s0.y + d0.y, s0.z + d0.z, s0.w + d0.w,
                  s1.x + d1.x, s1.y + d1.y, s1.z + d1.z, s1.w + d1.w};
    float4 o0, o1;
    o0.x = v[0] > 0.f ? v[0] : NEG_SLOPE * v[0];
    o0.y = v[1] > 0.f ? v[1] : NEG_SLOPE * v[1];
    o0.z = v[2] > 0.f ? v[2] : NEG_SLOPE * v[2];
    o0.w = v[3] > 0.f ? v[3] : NEG_SLOPE * v[3];
    o1.x = v[4] > 0.f ? v[4] : NEG_SLOPE * v[4];
    o1.y = v[5] > 0.f ? v[5] : NEG_SLOPE * v[5];
    o1.z = v[6] > 0.f ? v[6] : NEG_SLOPE * v[6];
    o1.w = v[7] > 0.f ? v[7] : NEG_SLOPE * v[7];
    *reinterpret_cast<float4*>(&evt[(size_t)e * 8]) = o0;
    *reinterpret_cast<float4*>(&evt[(size_t)e * 8 + 4]) = o1;
  } else {
    float v = als[s] + ald[d];
    evt[e] = v > 0.f ? v : NEG_SLOPE * v;
  }
}

// ---------------- softmax stats + in-place alpha normalization --------------
// thread per (node,head): max pass, sum pass, then write alpha = exp(v-m)*rs
// in place over evt. asel = normalized self-loop weight.

template <int HH>
__global__ __launch_bounds__(256) void msum_alpha(float* __restrict__ evt,
                                                  const float* __restrict__ selfe,
                                                  const int* __restrict__ rowptr,
                                                  float* __restrict__ asel, int n) {
  int idx = blockIdx.x * blockDim.x + threadIdx.x;
  if (idx >= n * HH) return;
  int node = idx / HH;
  int h = idx - node * HH;
  int r0 = rowptr[node], r1 = rowptr[node + 1];
  float e0 = selfe[idx];
  float m = e0;
  for (int p = r0; p < r1; ++p) m = fmaxf(m, evt[(size_t)p * HH + h]);
  float s = __expf(e0 - m);
  float a0 = s;
  for (int p = r0; p < r1; ++p) s += __expf(evt[(size_t)p * HH + h] - m);
  float rs = 1.f / (s + 1e-16f);
  asel[idx] = a0 * rs;
  for (int p = r0; p < r1; ++p) {
    size_t q = (size_t)p * HH + h;
    evt[q] = __expf(evt[q] - m) * rs;
  }
}

// ---------------- aggregation of INPUT features (layers 1-2) ----------------

// Layer 1: wave per node. lane: ch=lane&31, half=lane>>5 -> heads half*4..+3.
// AGG1[d, h, k] = asel*x[d,k] + sum_e alpha[e,h]*x[src,k]   (k<32)
__global__ __launch_bounds__(256) void agg1(const float* __restrict__ X,
                                            const float* __restrict__ alpha,
                                            const float* __restrict__ asel,
                                            const int* __restrict__ rowptr,
                                            const int* __restrict__ esrc,
                                            float* __restrict__ AGG, int n) {
  int node = blockIdx.x * 4 + (threadIdx.x >> 6);
  int lane = threadIdx.x & 63;
  if (node >= n) return;
  int ch = lane & 31;
  int half = lane >> 5;
  float xs = X[((unsigned)node << 5) + ch];
  float acc0 = asel[node * 8 + half * 4 + 0] * xs;
  float acc1 = asel[node * 8 + half * 4 + 1] * xs;
  float acc2 = asel[node * 8 + half * 4 + 2] * xs;
  float acc3 = asel[node * 8 + half * 4 + 3] * xs;
  int r0 = rowptr[node], r1 = rowptr[node + 1];
  int p = r0;
  for (; p + 2 <= r1; p += 2) {
    int s0 = esrc[p], s1 = esrc[p + 1];
    float xv0 = X[((unsigned)s0 << 5) + ch];
    float xv1 = X[((unsigned)s1 << 5) + ch];
    float4 a0 = *reinterpret_cast<const float4*>(&alpha[(size_t)p * 8 + half * 4]);
    float4 a1 = *reinterpret_cast<const float4*>(&alpha[(size_t)(p + 1) * 8 + half * 4]);
    acc0 += a0.x * xv0; acc1 += a0.y * xv0; acc2 += a0.z * xv0; acc3 += a0.w * xv0;
    acc0 += a1.x * xv1; acc1 += a1.y * xv1; acc2 += a1.z * xv1; acc3 += a1.w * xv1;
  }
  if (p < r1) {
    int s0 = esrc[p];
    float xv0 = X[((unsigned)s0 << 5) + ch];
    float4 a0 = *reinterpret_cast<const float4*>(&alpha[(size_t)p * 8 + half * 4]);
    acc0 += a0.x * xv0; acc1 += a0.y * xv0; acc2 += a0.z * xv0; acc3 += a0.w * xv0;
  }
  unsigned base = (unsigned)node * 256 + (unsigned)half * 128 + ch;
  AGG[base] = acc0;
  AGG[base + 32] = acc1;
  AGG[base + 64] = acc2;
  AGG[base + 96] = acc3;
}

// Layer 2: wave per node, lane = ch (64), acc[8] heads.
// AGG2[d, h, k] = asel*x1[d,k] + sum_e alpha[e,h]*x1[src,k]   (k<64)
__global__ __launch_bounds__(256) void agg2(const float* __restrict__ X,
                                            const float* __restrict__ alpha,
                                            const float* __restrict__ asel,
                                            const int* __restrict__ rowptr,
                                            const int* __restrict__ esrc,
                                            float* __restrict__ AGG, int n) {
  int node = blockIdx.x * 4 + (threadIdx.x >> 6);
  int lane = threadIdx.x & 63;
  if (node >= n) return;
  float acc[8];
  float xs = X[((unsigned)node << 6) + lane];
#pragma unroll
  for (int h = 0; h < 8; ++h) acc[h] = asel[node * 8 + h] * xs;
  int r0 = rowptr[node], r1 = rowptr[node + 1];
  int p = r0;
  for (; p + 2 <= r1; p += 2) {
    int s0 = esrc[p], s1 = esrc[p + 1];
    float xv0 = X[((unsigned)s0 << 6) + lane];
    float xv1 = X[((unsigned)s1 << 6) + lane];
    float4 a00 = *reinterpret_cast<const float4*>(&alpha[(size_t)p * 8]);
    float4 a01 = *reinterpret_cast<const float4*>(&alpha[(size_t)p * 8 + 4]);
    float4 a10 = *reinterpret_cast<const float4*>(&alpha[(size_t)(p + 1) * 8]);
    float4 a11 = *reinterpret_cast<const float4*>(&alpha[(size_t)(p + 1) * 8 + 4]);
    acc[0] += a00.x * xv0; acc[1] += a00.y * xv0;
    acc[2] += a00.z * xv0; acc[3] += a00.w * xv0;
    acc[4] += a01.x * xv0; acc[5] += a01.y * xv0;
    acc[6] += a01.z * xv0; acc[7] += a01.w * xv0;
    acc[0] += a10.x * xv1; acc[1] += a10.y * xv1;
    acc[2] += a10.z * xv1; acc[3] += a10.w * xv1;
    acc[4] += a11.x * xv1; acc[5] += a11.y * xv1;
    acc[6] += a11.z * xv1; acc[7] += a11.w * xv1;
  }
  if (p < r1) {
    int s0 = esrc[p];
    float xv0 = X[((unsigned)s0 << 6) + lane];
    float4 a00 = *reinterpret_cast<const float4*>(&alpha[(size_t)p * 8]);
    float4 a01 = *reinterpret_cast<const float4*>(&alpha[(size_t)p * 8 + 4]);
    acc[0] += a00.x * xv0; acc[1] += a00.y * xv0;
    acc[2] += a00.z * xv0; acc[3] += a00.w * xv0;
    acc[4] += a01.x * xv0; acc[5] += a01.y * xv0;
    acc[6] += a01.z * xv0; acc[7] += a01.w * xv0;
  }
  unsigned base = (unsigned)node * 512 + lane;
#pragma unroll
  for (int h = 0; h < 8; ++h) AGG[base + h * 64] = acc[h];
}

// ---------------- post-aggregation projections ------------------------------

// Layer 1: x1[d, h*8+c] = elu( sum_k AGG1[d,h,k]*W1[k,h*8+c] + b1 )
// wave per 8 nodes; lane=col(64), h=lane>>3.
__global__ __launch_bounds__(256) void proj1(const float* __restrict__ AGG,
                                             const float* __restrict__ W1,
                                             const float* __restrict__ b1,
                                             float* __restrict__ OUT, int n) {
  int w = blockIdx.x * 4 + (threadIdx.x >> 6);
  int lane = threadIdx.x & 63;
  int node0 = w * 8;
  if (node0 >= n) return;
  int h = lane >> 3;
  float acc[8];
#pragma unroll
  for (int j = 0; j < 8; ++j) acc[j] = 0.f;
  for (int k = 0; k < 32; ++k) {
    float wv = W1[k * 64 + lane];
#pragma unroll
    for (int j = 0; j < 8; ++j) {
      int nd = min(node0 + j, n - 1);
      acc[j] += AGG[(unsigned)nd * 256 + h * 32 + k] * wv;
    }
  }
  float bv = b1[lane];
#pragma unroll
  for (int j = 0; j < 8; ++j) {
    int nd = node0 + j;
    if (nd >= n) break;
    float v = acc[j] + bv;
    v = v > 0.f ? v : expm1f(v);
    OUT[(unsigned)nd * 64 + lane] = v;
  }
}

// Layer 2: x2[d, c] = elu( sum_k AGG2[d,h(c),k]*W2[k,c] + b2 ), c = lane*8..+7
// wave per 4 nodes.
__global__ __launch_bounds__(256) void proj2(const float* __restrict__ AGG,
                                             const float* __restrict__ W2,
                                             const float* __restrict__ b2,
                                             float* __restrict__ OUT, int n) {
  int w = blockIdx.x * 4 + (threadIdx.x >> 6);
  int lane = threadIdx.x & 63;
  int node0 = w * 4;
  if (node0 >= n) return;
  int c0 = lane * 8;
  int h = lane >> 3;
  float acc[4][8];
#pragma unroll
  for (int j = 0; j < 4; ++j)
#pragma unroll
    for (int c = 0; c < 8; ++c) acc[j][c] = 0.f;
  for (int k = 0; k < 64; ++k) {
    const float4 w0 = *reinterpret_cast<const float4*>(&W2[(size_t)k * 512 + c0]);
    const float4 w1 = *reinterpret_cast<const float4*>(&W2[(size_t)k * 512 + c0 + 4]);
#pragma unroll
    for (int j = 0; j < 4; ++j) {
      int nd = min(node0 + j, n - 1);
      float xv = AGG[(unsigned)nd * 512 + h * 64 + k];
      acc[j][0] += xv * w0.x; acc[j][1] += xv * w0.y;
      acc[j][2] += xv * w0.z; acc[j][3] += xv * w0.w;
      acc[j][4] += xv * w1.x; acc[j][5] += xv * w1.y;
      acc[j][6] += xv * w1.z; acc[j][7] += xv * w1.w;
    }
  }
  float4 bv0 = *reinterpret_cast<const float4*>(&b2[c0]);
  float4 bv1 = *reinterpret_cast<const float4*>(&b2[c0 + 4]);
#pragma unroll
  for (int j = 0; j < 4; ++j) {
    int nd = node0 + j;
    if (nd >= n) break;
    float v[8];
    v[0] = acc[j][0] + bv0.x; v[1] = acc[j][1] + bv0.y;
    v[2] = acc[j][2] + bv0.z; v[3] = acc[j][3] + bv0.w;
    v[4] = acc[j][4] + bv1.x; v[5] = acc[j][5] + bv1.y;
    v[6] = acc[j][6] + bv1.z; v[7] = acc[j][7] + bv1.w;
#pragma unroll
    for (int c = 0; c < 8; ++c) v[c] = v[c] > 0.f ? v[c] : expm1f(v[c]);
    float4* o = reinterpret_cast<float4*>(&OUT[(unsigned)nd * 512 + c0]);
    o[0] = make_float4(v[0], v[1], v[2], v[3]);
    o[1] = make_float4(v[4], v[5], v[6], v[7]);
  }
}

// Layer-3 GEMM: h3 = x2[n,512] @ W3[512,6]; wave per node, shuffle reduce.
__global__ __launch_bounds__(64) void gemm_l3(const float* __restrict__ X,
                                              const float* __restrict__ W,
                                              float* __restrict__ H, int n) {
  int node = blockIdx.x;
  int lane = threadIdx.x;
  if (node >= n) return;
  float acc[6] = {0.f, 0.f, 0.f, 0.f, 0.f, 0.f};
  for (int k = lane; k < 512; k += 64) {
    float xv = X[(size_t)node * 512 + k];
#pragma unroll
    for (int c = 0; c < 6; ++c) acc[c] += xv * W[k * 6 + c];
  }
#pragma unroll
  for (int c = 0; c < 6; ++c) {
    float v = acc[c];
    for (int off = 32; off >= 1; off >>= 1) v += __shfl_down(v, off, 64);
    if (lane == 0) H[(size_t)node * 6 + c] = v;
  }
}

// Layer-3 aggregate: wave per node; lanes 0..5 = channels; no ELU.
__global__ __launch_bounds__(256) void agg_l3(const float* __restrict__ HF,
                                              const float* __restrict__ alpha,
                                              const float* __restrict__ asel,
                                              const float* __restrict__ bias,
                                              const int* __restrict__ rowptr,
                                              const int* __restrict__ esrc,
                                              float* __restrict__ OUT, int n) {
  int node = blockIdx.x * 4 + (threadIdx.x >> 6);
  int lane = threadIdx.x & 63;
  if (node >= n) return;
  int ch = lane < 6 ? lane : 0;
  float acc = asel[node] * HF[(unsigned)node * 6u + ch];
  int r0 = rowptr[node], r1 = rowptr[node + 1];
  int p = r0;
  for (; p + 2 <= r1; p += 2) {
    int s0 = esrc[p], s1 = esrc[p + 1];
    float h0 = HF[(unsigned)s0 * 6u + ch];
    float h1 = HF[(unsigned)s1 * 6u + ch];
    float a0 = alpha[p], a1 = alpha[p + 1];
    acc += a0 * h0 + a1 * h1;
  }
  if (p < r1) acc += alpha[p] * HF[(unsigned)esrc[p] * 6u + ch];
  if (lane < 6) OUT[(unsigned)node * 6u + lane] = acc + bias[lane];
}

// ---------------- launch ----------------

extern "C" void kernel_launch(void* const* d_in, const int* in_sizes, int n_in,
                              void* d_out, int out_size, void* d_ws, size_t ws_size,
                              hipStream_t stream) {
  const float* x     = (const float*)d_in[0];
  const int*   ei    = (const int*)d_in[1];
  const float* W1    = (const float*)d_in[2];
  const float* asrc1 = (const float*)d_in[3];
  const float* adst1 = (const float*)d_in[4];
  const float* b1    = (const float*)d_in[5];
  const float* W2    = (const float*)d_in[6];
  const float* asrc2 = (const float*)d_in[7];
  const float* adst2 = (const float*)d_in[8];
  const float* b2    = (const float*)d_in[9];
  const float* W3    = (const float*)d_in[10];
  const float* asrc3 = (const float*)d_in[11];
  const float* adst3 = (const float*)d_in[12];
  const float* b3    = (const float*)d_in[13];
  float* outf = (float*)d_out;

  const int n = in_sizes[0] / 32;   // 10000
  const int E = in_sizes[1] / 2;    // 160000

  char* ws = (char*)d_ws;
  size_t off = 0;
  auto alloc = [&](size_t bytes) {
    size_t o = off;
    off = (off + bytes + 255) & ~(size_t)255;
    return ws + o;
  };
  int* deg     = (int*)alloc((size_t)n * 4);
  int* rowptr  = (int*)alloc((size_t)(n + 1) * 4);
  int* cursor  = (int*)alloc((size_t)n * 4);
  int* esrc    = (int*)alloc((size_t)E * 4);
  int* edst    = (int*)alloc((size_t)E * 4);
  float* evt   = (float*)alloc((size_t)E * 8 * 4);   // raw logits -> alpha, [E][8]
  float* selfe = (float*)alloc((size_t)n * 8 * 4);
  float* als   = (float*)alloc((size_t)n * 8 * 4);
  float* ald   = (float*)alloc((size_t)n * 8 * 4);
  float* asel  = (float*)alloc((size_t)n * 8 * 4);
  float* av    = (float*)alloc((size_t)1536 * 4);
  float* AGG1  = (float*)alloc((size_t)n * 256 * 4);
  float* x1    = (float*)alloc((size_t)n * 64 * 4);
  float* AGG2  = (float*)alloc((size_t)n * 512 * 4);
  float* x2    = (float*)alloc((size_t)n * 512 * 4);
  float* h3    = (float*)alloc((size_t)n * 6 * 4);

  // ---- CSR build (shared by all layers) + attention vectors ----
  hipMemsetAsync(deg, 0, (size_t)n * 4, stream);
  count_deg<<<(E + 255) / 256, 256, 0, stream>>>(ei, deg, E);
  scan_k<<<1, 1024, 0, stream>>>(deg, rowptr, cursor, n);
  fill_edges<<<(E + 255) / 256, 256, 0, stream>>>(ei, cursor, esrc, edst, E);
  prep_av<<<2, 512, 0, stream>>>(W1, asrc1, adst1, W2, asrc2, adst2, av);

  // ---- layer 1: 32 -> 8x8, concat, ELU ----
  logits_x<8, 32><<<(n * 8 + 255) / 256, 256, 0, stream>>>(x, av, av + 256, als, ald, selfe, n);
  edge_e<8><<<(E + 255) / 256, 256, 0, stream>>>(esrc, edst, als, ald, evt, E);
  msum_alpha<8><<<(n * 8 + 255) / 256, 256, 0, stream>>>(evt, selfe, rowptr, asel, n);
  agg1<<<(n + 3) / 4, 256, 0, stream>>>(x, evt, asel, rowptr, esrc, AGG1, n);
  proj1<<<(n / 8 + 3) / 4 + 1, 256, 0, stream>>>(AGG1, W1, b1, x1, n);

  // ---- layer 2: 64 -> 8x64, concat, ELU ----
  logits_x<8, 64><<<(n * 8 + 255) / 256, 256, 0, stream>>>(x1, av + 512, av + 1024, als, ald, selfe, n);
  edge_e<8><<<(E + 255) / 256, 256, 0, stream>>>(esrc, edst, als, ald, evt, E);
  msum_alpha<8><<<(n * 8 + 255) / 256, 256, 0, stream>>>(evt, selfe, rowptr, asel, n);
  agg2<<<(n + 3) / 4, 256, 0, stream>>>(x1, evt, asel, rowptr, esrc, AGG2, n);
  proj2<<<(n / 4 + 3) / 4 + 1, 256, 0, stream>>>(AGG2, W2, b2, x2, n);

  // ---- layer 3: 512 -> 6, 1 head, no ELU ----
  gemm_l3<<<n, 64, 0, stream>>>(x2, W3, h3, n);
  logits_h3<<<(n + 255) / 256, 256, 0, stream>>>(h3, asrc3, adst3, als, ald, selfe, n);
  edge_e<1><<<(E + 255) / 256, 256, 0, stream>>>(esrc, edst, als, ald, evt, E);
  msum_alpha<1><<<(n + 255) / 256, 256, 0, stream>>>(evt, selfe, rowptr, asel, n);
  agg_l3<<<(n + 3) / 4, 256, 0, stream>>>(h3, evt, asel, b3, rowptr, esrc, outf, n);
}

// Round 5
// 256.353 us; speedup vs baseline: 1.2221x; 1.2221x over previous
//
#include <hip/hip_runtime.h>
#include <hip/hip_bf16.h>
#include <math.h>

// ---------------------------------------------------------------------------
// 3-layer GAT (PyG GATConv semantics, self-loops, eval mode).
// Round-5: linearity structure (aggregate small input rows, project after),
// consolidated to 15 dispatches:
//   memset deg | count_deg | scan3(scan+prep_av) | fill_edges |
//   L1: logits_x, msum_alpha8 (fused edge-logit recompute, wave-parallel),
//       agg1 (edge-slot split), proj1
//   L2: logits_x, msum_alpha8, agg2 (4-unroll), proj2
//   L3: gemm_l3+logits (fused), msum_alpha1, agg_l3 -> d_out
// ---------------------------------------------------------------------------

#define NEG_SLOPE 0.2f

__device__ __forceinline__ float lrelu(float v) {
  return v > 0.f ? v : NEG_SLOPE * v;
}

// ---------------- CSR build ----------------

__global__ __launch_bounds__(256) void count_deg(const int* __restrict__ ei,
                                                 int* __restrict__ deg, int E) {
  int e = blockIdx.x * blockDim.x + threadIdx.x;
  if (e < E) atomicAdd(&deg[ei[E + e]], 1);  // ei[E+e] = dst
}

// block 0: exclusive scan of deg -> rowptr/cursor. blocks 1-2: prep_av.
// avs1 -> av[0..256), avd1 -> av[256..512), avs2 -> av[512..1024), avd2 -> av[1024..1536)
__global__ __launch_bounds__(1024) void scan3(const int* __restrict__ deg,
                                              int* __restrict__ rowptr,
                                              int* __restrict__ cursor, int n,
                                              const float* __restrict__ W1,
                                              const float* __restrict__ as1,
                                              const float* __restrict__ ad1,
                                              const float* __restrict__ W2,
                                              const float* __restrict__ as2,
                                              const float* __restrict__ ad2,
                                              float* __restrict__ av) {
  int t = threadIdx.x;
  if (blockIdx.x == 0) {
    __shared__ int part[1024];
    int chunk = (n + 1023) >> 10;
    int lo = t * chunk;
    int hi = min(lo + chunk, n);
    int s = 0;
    for (int i = lo; i < hi; ++i) s += deg[i];
    part[t] = s;
    __syncthreads();
    for (int off = 1; off < 1024; off <<= 1) {
      int v = (t >= off) ? part[t - off] : 0;
      __syncthreads();
      part[t] += v;
      __syncthreads();
    }
    int run = (t == 0) ? 0 : part[t - 1];
    for (int i = lo; i < hi; ++i) {
      rowptr[i] = run;
      cursor[i] = run;
      run += deg[i];
    }
    if (t == 1023) rowptr[n] = part[1023];
  } else if (blockIdx.x == 1) {
    if (t < 256) {
      int h = t >> 5, k = t & 31;
      float s = 0.f, d = 0.f;
#pragma unroll
      for (int c = 0; c < 8; ++c) {
        float w = W1[k * 64 + h * 8 + c];
        s += w * as1[h * 8 + c];
        d += w * ad1[h * 8 + c];
      }
      av[t] = s;
      av[256 + t] = d;
    }
  } else {
    if (t < 512) {
      int h = t >> 6, k = t & 63;
      float s = 0.f, d = 0.f;
#pragma unroll
      for (int c = 0; c < 64; ++c) {
        float w = W2[k * 512 + h * 64 + c];
        s += w * as2[h * 64 + c];
        d += w * ad2[h * 64 + c];
      }
      av[512 + t] = s;
      av[1024 + t] = d;
    }
  }
}

__global__ __launch_bounds__(256) void fill_edges(const int* __restrict__ ei,
                                                  int* __restrict__ cursor,
                                                  int* __restrict__ esrc, int E) {
  int e = blockIdx.x * blockDim.x + threadIdx.x;
  if (e < E) {
    int d = ei[E + e];
    int pos = atomicAdd(&cursor[d], 1);
    esrc[pos] = ei[e];  // src; dst implicit via CSR row
  }
}

// ---------------- logits from input features x ------------------------------

template <int HH, int K>
__global__ __launch_bounds__(256) void logits_x(const float* __restrict__ X,
                                                const float* __restrict__ avs,
                                                const float* __restrict__ avd,
                                                float* __restrict__ als,
                                                float* __restrict__ ald,
                                                float* __restrict__ selfe, int n) {
  int idx = blockIdx.x * blockDim.x + threadIdx.x;
  if (idx >= n * HH) return;
  int node = idx / HH;
  int h = idx - node * HH;
  const float* xr = X + (size_t)node * K;
  const float* vs = avs + h * K;
  const float* vd = avd + h * K;
  float s0 = 0.f, s1 = 0.f;
#pragma unroll
  for (int k4 = 0; k4 < K / 4; ++k4) {
    float4 xv = *reinterpret_cast<const float4*>(&xr[k4 * 4]);
    float4 a = *reinterpret_cast<const float4*>(&vs[k4 * 4]);
    float4 b = *reinterpret_cast<const float4*>(&vd[k4 * 4]);
    s0 += xv.x * a.x + xv.y * a.y + xv.z * a.z + xv.w * a.w;
    s1 += xv.x * b.x + xv.y * b.y + xv.z * b.z + xv.w * b.w;
  }
  als[idx] = s0;
  ald[idx] = s1;
  float e = s0 + s1;
  selfe[idx] = lrelu(e);
}

// ---------------- softmax stats + alpha, fused edge logits ------------------
// HH=8: wave per node. lane -> (i = lane>>3 edge-slot, h = lane&7).
// Three passes over the row, recomputing lrelu(als[src]+ald[dst]) each time;
// writes alpha[p*8+h] (32B-coalesced per slot) and asel[node*8+h].

__global__ __launch_bounds__(256) void msum_alpha8(const int* __restrict__ esrc,
                                                   const float* __restrict__ als,
                                                   const float* __restrict__ ald,
                                                   const float* __restrict__ selfe,
                                                   const int* __restrict__ rowptr,
                                                   float* __restrict__ alpha,
                                                   float* __restrict__ asel, int n) {
  int node = blockIdx.x * 4 + (threadIdx.x >> 6);
  int lane = threadIdx.x & 63;
  if (node >= n) return;
  int i = lane >> 3;
  int h = lane & 7;
  float aldv = ald[node * 8 + h];
  float e0 = selfe[node * 8 + h];
  int r0 = rowptr[node], r1 = rowptr[node + 1];

  // pass 1: max
  float m = e0;
  for (int p = r0 + i; p < r1; p += 8)
    m = fmaxf(m, lrelu(als[esrc[p] * 8 + h] + aldv));
  m = fmaxf(m, __shfl_xor(m, 8, 64));
  m = fmaxf(m, __shfl_xor(m, 16, 64));
  m = fmaxf(m, __shfl_xor(m, 32, 64));

  // pass 2: sum
  float s = 0.f;
  for (int p = r0 + i; p < r1; p += 8)
    s += __expf(lrelu(als[esrc[p] * 8 + h] + aldv) - m);
  s += __shfl_xor(s, 8, 64);
  s += __shfl_xor(s, 16, 64);
  s += __shfl_xor(s, 32, 64);
  float a0 = __expf(e0 - m);
  float rs = 1.f / (s + a0 + 1e-16f);
  if (lane < 8) asel[node * 8 + lane] = a0 * rs;

  // pass 3: write normalized alpha
  for (int p = r0 + i; p < r1; p += 8)
    alpha[(size_t)p * 8 + h] = __expf(lrelu(als[esrc[p] * 8 + h] + aldv) - m) * rs;
}

// HH=1 (layer 3): wave per node, lane = edge slot.
__global__ __launch_bounds__(256) void msum_alpha1(const int* __restrict__ esrc,
                                                   const float* __restrict__ als,
                                                   const float* __restrict__ ald,
                                                   const float* __restrict__ selfe,
                                                   const int* __restrict__ rowptr,
                                                   float* __restrict__ alpha,
                                                   float* __restrict__ asel, int n) {
  int node = blockIdx.x * 4 + (threadIdx.x >> 6);
  int lane = threadIdx.x & 63;
  if (node >= n) return;
  float aldv = ald[node];
  float e0 = selfe[node];
  int r0 = rowptr[node], r1 = rowptr[node + 1];

  float m = e0;
  for (int p = r0 + lane; p < r1; p += 64)
    m = fmaxf(m, lrelu(als[esrc[p]] + aldv));
#pragma unroll
  for (int off = 1; off < 64; off <<= 1) m = fmaxf(m, __shfl_xor(m, off, 64));

  float s = 0.f;
  for (int p = r0 + lane; p < r1; p += 64)
    s += __expf(lrelu(als[esrc[p]] + aldv) - m);
#pragma unroll
  for (int off = 1; off < 64; off <<= 1) s += __shfl_xor(s, off, 64);
  float a0 = __expf(e0 - m);
  float rs = 1.f / (s + a0 + 1e-16f);
  if (lane == 0) asel[node] = a0 * rs;

  for (int p = r0 + lane; p < r1; p += 64)
    alpha[p] = __expf(lrelu(als[esrc[p]] + aldv) - m) * rs;
}

// ---------------- aggregation of INPUT features (layers 1-2) ----------------

// Layer 1: wave per node; lane -> (ch = lane&31, eslot = lane>>5).
// Each slot walks every other edge; xor-32 reduce at end.
__global__ __launch_bounds__(256) void agg1(const float* __restrict__ X,
                                            const float* __restrict__ alpha,
                                            const float* __restrict__ asel,
                                            const int* __restrict__ rowptr,
                                            const int* __restrict__ esrc,
                                            float* __restrict__ AGG, int n) {
  int node = blockIdx.x * 4 + (threadIdx.x >> 6);
  int lane = threadIdx.x & 63;
  if (node >= n) return;
  int ch = lane & 31;
  int eslot = lane >> 5;
  float acc[8];
  if (eslot == 0) {
    float xs = X[((unsigned)node << 5) + ch];
#pragma unroll
    for (int h = 0; h < 8; ++h) acc[h] = asel[node * 8 + h] * xs;
  } else {
#pragma unroll
    for (int h = 0; h < 8; ++h) acc[h] = 0.f;
  }
  int r0 = rowptr[node], r1 = rowptr[node + 1];
  int p = r0 + eslot;
  for (; p + 2 < r1; p += 4) {
    int s0 = esrc[p], s1 = esrc[p + 2];
    float xv0 = X[((unsigned)s0 << 5) + ch];
    float xv1 = X[((unsigned)s1 << 5) + ch];
    float4 a00 = *reinterpret_cast<const float4*>(&alpha[(size_t)p * 8]);
    float4 a01 = *reinterpret_cast<const float4*>(&alpha[(size_t)p * 8 + 4]);
    float4 a10 = *reinterpret_cast<const float4*>(&alpha[(size_t)(p + 2) * 8]);
    float4 a11 = *reinterpret_cast<const float4*>(&alpha[(size_t)(p + 2) * 8 + 4]);
    acc[0] += a00.x * xv0; acc[1] += a00.y * xv0;
    acc[2] += a00.z * xv0; acc[3] += a00.w * xv0;
    acc[4] += a01.x * xv0; acc[5] += a01.y * xv0;
    acc[6] += a01.z * xv0; acc[7] += a01.w * xv0;
    acc[0] += a10.x * xv1; acc[1] += a10.y * xv1;
    acc[2] += a10.z * xv1; acc[3] += a10.w * xv1;
    acc[4] += a11.x * xv1; acc[5] += a11.y * xv1;
    acc[6] += a11.z * xv1; acc[7] += a11.w * xv1;
  }
  if (p < r1) {
    int s0 = esrc[p];
    float xv0 = X[((unsigned)s0 << 5) + ch];
    float4 a00 = *reinterpret_cast<const float4*>(&alpha[(size_t)p * 8]);
    float4 a01 = *reinterpret_cast<const float4*>(&alpha[(size_t)p * 8 + 4]);
    acc[0] += a00.x * xv0; acc[1] += a00.y * xv0;
    acc[2] += a00.z * xv0; acc[3] += a00.w * xv0;
    acc[4] += a01.x * xv0; acc[5] += a01.y * xv0;
    acc[6] += a01.z * xv0; acc[7] += a01.w * xv0;
  }
#pragma unroll
  for (int h = 0; h < 8; ++h) acc[h] += __shfl_xor(acc[h], 32, 64);
  if (eslot == 0) {
    unsigned base = (unsigned)node * 256 + ch;
#pragma unroll
    for (int h = 0; h < 8; ++h) AGG[base + h * 32] = acc[h];
  }
}

// Layer 2: wave per node, lane = ch (64), acc[8] heads, 4-edge unroll.
__global__ __launch_bounds__(256) void agg2(const float* __restrict__ X,
                                            const float* __restrict__ alpha,
                                            const float* __restrict__ asel,
                                            const int* __restrict__ rowptr,
                                            const int* __restrict__ esrc,
                                            float* __restrict__ AGG, int n) {
  int node = blockIdx.x * 4 + (threadIdx.x >> 6);
  int lane = threadIdx.x & 63;
  if (node >= n) return;
  float acc[8];
  float xs = X[((unsigned)node << 6) + lane];
#pragma unroll
  for (int h = 0; h < 8; ++h) acc[h] = asel[node * 8 + h] * xs;
  int r0 = rowptr[node], r1 = rowptr[node + 1];
  int p = r0;
  for (; p + 4 <= r1; p += 4) {
    int s0 = esrc[p], s1 = esrc[p + 1], s2 = esrc[p + 2], s3 = esrc[p + 3];
    float xv0 = X[((unsigned)s0 << 6) + lane];
    float xv1 = X[((unsigned)s1 << 6) + lane];
    float xv2 = X[((unsigned)s2 << 6) + lane];
    float xv3 = X[((unsigned)s3 << 6) + lane];
#pragma unroll
    for (int q = 0; q < 4; ++q) {
      float xv = q == 0 ? xv0 : q == 1 ? xv1 : q == 2 ? xv2 : xv3;
      float4 a0 = *reinterpret_cast<const float4*>(&alpha[(size_t)(p + q) * 8]);
      float4 a1 = *reinterpret_cast<const float4*>(&alpha[(size_t)(p + q) * 8 + 4]);
      acc[0] += a0.x * xv; acc[1] += a0.y * xv;
      acc[2] += a0.z * xv; acc[3] += a0.w * xv;
      acc[4] += a1.x * xv; acc[5] += a1.y * xv;
      acc[6] += a1.z * xv; acc[7] += a1.w * xv;
    }
  }
  for (; p < r1; ++p) {
    int s0 = esrc[p];
    float xv = X[((unsigned)s0 << 6) + lane];
    float4 a0 = *reinterpret_cast<const float4*>(&alpha[(size_t)p * 8]);
    float4 a1 = *reinterpret_cast<const float4*>(&alpha[(size_t)p * 8 + 4]);
    acc[0] += a0.x * xv; acc[1] += a0.y * xv;
    acc[2] += a0.z * xv; acc[3] += a0.w * xv;
    acc[4] += a1.x * xv; acc[5] += a1.y * xv;
    acc[6] += a1.z * xv; acc[7] += a1.w * xv;
  }
  unsigned base = (unsigned)node * 512 + lane;
#pragma unroll
  for (int h = 0; h < 8; ++h) AGG[base + h * 64] = acc[h];
}

// ---------------- post-aggregation projections ------------------------------

// Layer 1: x1[d, h*8+c] = elu( sum_k AGG1[d,h,k]*W1[k,h*8+c] + b1 )
__global__ __launch_bounds__(256) void proj1(const float* __restrict__ AGG,
                                             const float* __restrict__ W1,
                                             const float* __restrict__ b1,
                                             float* __restrict__ OUT, int n) {
  int w = blockIdx.x * 4 + (threadIdx.x >> 6);
  int lane = threadIdx.x & 63;
  int node0 = w * 8;
  if (node0 >= n) return;
  int h = lane >> 3;
  float acc[8];
#pragma unroll
  for (int j = 0; j < 8; ++j) acc[j] = 0.f;
  for (int k = 0; k < 32; ++k) {
    float wv = W1[k * 64 + lane];
#pragma unroll
    for (int j = 0; j < 8; ++j) {
      int nd = min(node0 + j, n - 1);
      acc[j] += AGG[(unsigned)nd * 256 + h * 32 + k] * wv;
    }
  }
  float bv = b1[lane];
#pragma unroll
  for (int j = 0; j < 8; ++j) {
    int nd = node0 + j;
    if (nd >= n) break;
    float v = acc[j] + bv;
    v = v > 0.f ? v : expm1f(v);
    OUT[(unsigned)nd * 64 + lane] = v;
  }
}

// Layer 2: x2[d, c] = elu( sum_k AGG2[d,h(c),k]*W2[k,c] + b2 ), c=lane*8..+7
__global__ __launch_bounds__(256) void proj2(const float* __restrict__ AGG,
                                             const float* __restrict__ W2,
                                             const float* __restrict__ b2,
                                             float* __restrict__ OUT, int n) {
  int w = blockIdx.x * 4 + (threadIdx.x >> 6);
  int lane = threadIdx.x & 63;
  int node0 = w * 4;
  if (node0 >= n) return;
  int c0 = lane * 8;
  int h = lane >> 3;
  float acc[4][8];
#pragma unroll
  for (int j = 0; j < 4; ++j)
#pragma unroll
    for (int c = 0; c < 8; ++c) acc[j][c] = 0.f;
  for (int k = 0; k < 64; ++k) {
    const float4 w0 = *reinterpret_cast<const float4*>(&W2[(size_t)k * 512 + c0]);
    const float4 w1 = *reinterpret_cast<const float4*>(&W2[(size_t)k * 512 + c0 + 4]);
#pragma unroll
    for (int j = 0; j < 4; ++j) {
      int nd = min(node0 + j, n - 1);
      float xv = AGG[(unsigned)nd * 512 + h * 64 + k];
      acc[j][0] += xv * w0.x; acc[j][1] += xv * w0.y;
      acc[j][2] += xv * w0.z; acc[j][3] += xv * w0.w;
      acc[j][4] += xv * w1.x; acc[j][5] += xv * w1.y;
      acc[j][6] += xv * w1.z; acc[j][7] += xv * w1.w;
    }
  }
  float4 bv0 = *reinterpret_cast<const float4*>(&b2[c0]);
  float4 bv1 = *reinterpret_cast<const float4*>(&b2[c0 + 4]);
#pragma unroll
  for (int j = 0; j < 4; ++j) {
    int nd = node0 + j;
    if (nd >= n) break;
    float v[8];
    v[0] = acc[j][0] + bv0.x; v[1] = acc[j][1] + bv0.y;
    v[2] = acc[j][2] + bv0.z; v[3] = acc[j][3] + bv0.w;
    v[4] = acc[j][4] + bv1.x; v[5] = acc[j][5] + bv1.y;
    v[6] = acc[j][6] + bv1.z; v[7] = acc[j][7] + bv1.w;
#pragma unroll
    for (int c = 0; c < 8; ++c) v[c] = v[c] > 0.f ? v[c] : expm1f(v[c]);
    float4* o = reinterpret_cast<float4*>(&OUT[(unsigned)nd * 512 + c0]);
    o[0] = make_float4(v[0], v[1], v[2], v[3]);
    o[1] = make_float4(v[4], v[5], v[6], v[7]);
  }
}

// Layer-3 GEMM fused with logits: h3 = x2 @ W3 (512->6); lane-split K,
// shuffle reduce; lane 0 writes h3 row + als/ald/selfe.
__global__ __launch_bounds__(256) void gemm_l3f(const float* __restrict__ X,
                                                const float* __restrict__ W,
                                                const float* __restrict__ As,
                                                const float* __restrict__ Ad,
                                                float* __restrict__ H,
                                                float* __restrict__ als,
                                                float* __restrict__ ald,
                                                float* __restrict__ selfe, int n) {
  int node = blockIdx.x * 4 + (threadIdx.x >> 6);
  int lane = threadIdx.x & 63;
  if (node >= n) return;
  float acc[6] = {0.f, 0.f, 0.f, 0.f, 0.f, 0.f};
  for (int k = lane; k < 512; k += 64) {
    float xv = X[(size_t)node * 512 + k];
#pragma unroll
    for (int c = 0; c < 6; ++c) acc[c] += xv * W[k * 6 + c];
  }
#pragma unroll
  for (int c = 0; c < 6; ++c) {
#pragma unroll
    for (int off = 32; off >= 1; off >>= 1)
      acc[c] += __shfl_down(acc[c], off, 64);
  }
  if (lane == 0) {
    float s0 = 0.f, s1 = 0.f;
#pragma unroll
    for (int c = 0; c < 6; ++c) {
      H[(size_t)node * 6 + c] = acc[c];
      s0 += acc[c] * As[c];
      s1 += acc[c] * Ad[c];
    }
    als[node] = s0;
    ald[node] = s1;
    selfe[node] = lrelu(s0 + s1);
  }
}

// Layer-3 aggregate: wave per node; lanes 0..5 = channels; no ELU.
__global__ __launch_bounds__(256) void agg_l3(const float* __restrict__ HF,
                                              const float* __restrict__ alpha,
                                              const float* __restrict__ asel,
                                              const float* __restrict__ bias,
                                              const int* __restrict__ rowptr,
                                              const int* __restrict__ esrc,
                                              float* __restrict__ OUT, int n) {
  int node = blockIdx.x * 4 + (threadIdx.x >> 6);
  int lane = threadIdx.x & 63;
  if (node >= n) return;
  int ch = lane < 6 ? lane : 0;
  float acc = asel[node] * HF[(unsigned)node * 6u + ch];
  int r0 = rowptr[node], r1 = rowptr[node + 1];
  int p = r0;
  for (; p + 2 <= r1; p += 2) {
    int s0 = esrc[p], s1 = esrc[p + 1];
    float h0 = HF[(unsigned)s0 * 6u + ch];
    float h1 = HF[(unsigned)s1 * 6u + ch];
    acc += alpha[p] * h0 + alpha[p + 1] * h1;
  }
  if (p < r1) acc += alpha[p] * HF[(unsigned)esrc[p] * 6u + ch];
  if (lane < 6) OUT[(unsigned)node * 6u + lane] = acc + bias[lane];
}

// ---------------- launch ----------------

extern "C" void kernel_launch(void* const* d_in, const int* in_sizes, int n_in,
                              void* d_out, int out_size, void* d_ws, size_t ws_size,
                              hipStream_t stream) {
  const float* x     = (const float*)d_in[0];
  const int*   ei    = (const int*)d_in[1];
  const float* W1    = (const float*)d_in[2];
  const float* asrc1 = (const float*)d_in[3];
  const float* adst1 = (const float*)d_in[4];
  const float* b1    = (const float*)d_in[5];
  const float* W2    = (const float*)d_in[6];
  const float* asrc2 = (const float*)d_in[7];
  const float* adst2 = (const float*)d_in[8];
  const float* b2    = (const float*)d_in[9];
  const float* W3    = (const float*)d_in[10];
  const float* asrc3 = (const float*)d_in[11];
  const float* adst3 = (const float*)d_in[12];
  const float* b3    = (const float*)d_in[13];
  float* outf = (float*)d_out;

  const int n = in_sizes[0] / 32;   // 10000
  const int E = in_sizes[1] / 2;    // 160000

  char* ws = (char*)d_ws;
  size_t off = 0;
  auto alloc = [&](size_t bytes) {
    size_t o = off;
    off = (off + bytes + 255) & ~(size_t)255;
    return ws + o;
  };
  int* deg     = (int*)alloc((size_t)n * 4);
  int* rowptr  = (int*)alloc((size_t)(n + 1) * 4);
  int* cursor  = (int*)alloc((size_t)n * 4);
  int* esrc    = (int*)alloc((size_t)E * 4);
  float* alpha = (float*)alloc((size_t)E * 8 * 4);   // [E][8] normalized
  float* selfe = (float*)alloc((size_t)n * 8 * 4);
  float* als   = (float*)alloc((size_t)n * 8 * 4);
  float* ald   = (float*)alloc((size_t)n * 8 * 4);
  float* asel  = (float*)alloc((size_t)n * 8 * 4);
  float* av    = (float*)alloc((size_t)1536 * 4);
  float* AGG1  = (float*)alloc((size_t)n * 256 * 4);
  float* x1    = (float*)alloc((size_t)n * 64 * 4);
  float* AGG2  = (float*)alloc((size_t)n * 512 * 4);
  float* x2    = (float*)alloc((size_t)n * 512 * 4);
  float* h3    = (float*)alloc((size_t)n * 6 * 4);

  int nb4 = (n + 3) / 4;  // 4 waves/block kernels

  // ---- CSR build + attention vectors ----
  hipMemsetAsync(deg, 0, (size_t)n * 4, stream);
  count_deg<<<(E + 255) / 256, 256, 0, stream>>>(ei, deg, E);
  scan3<<<3, 1024, 0, stream>>>(deg, rowptr, cursor, n,
                                W1, asrc1, adst1, W2, asrc2, adst2, av);
  fill_edges<<<(E + 255) / 256, 256, 0, stream>>>(ei, cursor, esrc, E);

  // ---- layer 1: 32 -> 8x8, concat, ELU ----
  logits_x<8, 32><<<(n * 8 + 255) / 256, 256, 0, stream>>>(x, av, av + 256, als, ald, selfe, n);
  msum_alpha8<<<nb4, 256, 0, stream>>>(esrc, als, ald, selfe, rowptr, alpha, asel, n);
  agg1<<<nb4, 256, 0, stream>>>(x, alpha, asel, rowptr, esrc, AGG1, n);
  proj1<<<(n / 8 + 3) / 4 + 1, 256, 0, stream>>>(AGG1, W1, b1, x1, n);

  // ---- layer 2: 64 -> 8x64, concat, ELU ----
  logits_x<8, 64><<<(n * 8 + 255) / 256, 256, 0, stream>>>(x1, av + 512, av + 1024, als, ald, selfe, n);
  msum_alpha8<<<nb4, 256, 0, stream>>>(esrc, als, ald, selfe, rowptr, alpha, asel, n);
  agg2<<<nb4, 256, 0, stream>>>(x1, alpha, asel, rowptr, esrc, AGG2, n);
  proj2<<<(n / 4 + 3) / 4 + 1, 256, 0, stream>>>(AGG2, W2, b2, x2, n);

  // ---- layer 3: 512 -> 6, 1 head, no ELU ----
  gemm_l3f<<<nb4, 256, 0, stream>>>(x2, W3, asrc3, adst3, h3, als, ald, selfe, n);
  msum_alpha1<<<nb4, 256, 0, stream>>>(esrc, als, ald, selfe, rowptr, alpha, asel, n);
  agg_l3<<<nb4, 256, 0, stream>>>(h3, alpha, asel, b3, rowptr, esrc, outf, n);
}